// Round 5
// baseline (121.848 us; speedup 1.0000x reference)
//
#include <hip/hip_runtime.h>

// DirectTuckerNet forward: out[i, k*J + j] = sum_{p,q} M[i,p,q] * C[k,p] * B[j,q]
// with M = (A @ G).reshape(I, R3, R2).  I=J=K=512, R1=R2=R3=4.
//
//   W[c]  = sum_r A[i,r] * G[r,c]          (once per thread; i = blockIdx.x)
//   v[q]  = sum_p C[k,p] * W[p*4+q]        (per row)
//   out[i,k,j] = sum_q v[q] * B[j,q]       (4 FMA per element)
//
// Persistent single-generation launch: 512 blocks = exactly 2 resident per CU
// (8 waves/CU at 256 thr/block), no block refill, no ragged tail generations.
// Block b owns the full i=b slice: 512 rows x 2KB = 1 MiB contiguous output.
// Each thread: 64 rows x 16 j's, NT f32x4 stores (512B/wave-half segments).

#define J_DIM 512

typedef float f32x4 __attribute__((ext_vector_type(4)));

__global__ __launch_bounds__(256) void tucker_fwd(
    const float* __restrict__ A, const float* __restrict__ B,
    const float* __restrict__ C, const float* __restrict__ G,
    float* __restrict__ out)
{
    const int tid = threadIdx.x;
    const int jlane = tid & 31;      // 32 j-lanes cover 512 j's (16 j each)
    const int rslot = tid >> 5;      // 8 row-slots x 64 rows = 512 rows per block
    const int i = blockIdx.x;        // one full i-slice per block

    // Load this thread's 16 B rows (j = s*128 + jlane*4 + e) into registers.
    const float4* B4 = reinterpret_cast<const float4*>(B);
    float4 b[4][4];
#pragma unroll
    for (int s = 0; s < 4; ++s) {
        const int j0 = s * 128 + jlane * 4;
#pragma unroll
        for (int e = 0; e < 4; ++e) b[s][e] = B4[j0 + e];
    }

    // W = row i of A@G (16 values), c = p*4 + q  (G is (4,16) row-major)
    const float4 a = reinterpret_cast<const float4*>(A)[i];
    float W[16];
#pragma unroll
    for (int c = 0; c < 16; ++c)
        W[c] = a.x * G[c] + a.y * G[16 + c] + a.z * G[32 + c] + a.w * G[48 + c];

    const float4* C4 = reinterpret_cast<const float4*>(C);
    const int k0 = rslot * 64;
    f32x4* obase = reinterpret_cast<f32x4*>(out + ((size_t)i * 512 + k0) * J_DIM);

#pragma unroll 4
    for (int rr = 0; rr < 64; ++rr) {
        const float4 ck = C4[k0 + rr];
        const float v0 = ck.x * W[0] + ck.y * W[4] + ck.z * W[8]  + ck.w * W[12];
        const float v1 = ck.x * W[1] + ck.y * W[5] + ck.z * W[9]  + ck.w * W[13];
        const float v2 = ck.x * W[2] + ck.y * W[6] + ck.z * W[10] + ck.w * W[14];
        const float v3 = ck.x * W[3] + ck.y * W[7] + ck.z * W[11] + ck.w * W[15];

#pragma unroll
        for (int s = 0; s < 4; ++s) {
            f32x4 o;
            o.x = v0 * b[s][0].x + v1 * b[s][0].y + v2 * b[s][0].z + v3 * b[s][0].w;
            o.y = v0 * b[s][1].x + v1 * b[s][1].y + v2 * b[s][1].z + v3 * b[s][1].w;
            o.z = v0 * b[s][2].x + v1 * b[s][2].y + v2 * b[s][2].z + v3 * b[s][2].w;
            o.w = v0 * b[s][3].x + v1 * b[s][3].y + v2 * b[s][3].z + v3 * b[s][3].w;
            __builtin_nontemporal_store(o, &obase[(size_t)rr * 128 + s * 32 + jlane]);
        }
    }
}

extern "C" void kernel_launch(void* const* d_in, const int* in_sizes, int n_in,
                              void* d_out, int out_size, void* d_ws, size_t ws_size,
                              hipStream_t stream) {
    const float* A = (const float*)d_in[0];   // (512, 4)
    const float* B = (const float*)d_in[1];   // (512, 4)
    const float* C = (const float*)d_in[2];   // (512, 4)
    const float* G = (const float*)d_in[3];   // (4, 16)
    float* out = (float*)d_out;               // (512, 512*512) f32

    tucker_fwd<<<512, 256, 0, stream>>>(A, B, C, G, out);
}

// Round 6
// 103.372 us; speedup vs baseline: 1.1787x; 1.1787x over previous
//
#include <hip/hip_runtime.h>

// DirectTuckerNet forward: out[i, k*J + j] = sum_{p,q} M[i,p,q] * C[k,p] * B[j,q]
// with M = (A @ G).reshape(I, R3, R2).  I=J=K=512, R1=R2=R3=4.
//
//   W[c]  = sum_r A[i,r] * G[r,c]          (once per thread; i uniform per block)
//   v[q]  = sum_p C[k,p] * W[p*4+q]        (per row)
//   out[i,k,j] = sum_q v[q] * B[j,q]       (4 FMA per element)
//
// R5 lesson: achieved write BW scales with resident waves/CU (8 w/CU -> 4.4TB/s,
// 16 w/CU -> 5.6TB/s). This version targets 32 waves/CU: 4-j-per-thread layout
// shrinks the B-register block from 64 to 16 VGPRs; __launch_bounds__(256,8)
// forces VGPR<=64 so 8 waves/SIMD fit. 4096 blocks x 256 thr, 32 rows/thread,
// 1KB contiguous NT wave-stores.

#define J_DIM 512

typedef float f32x4 __attribute__((ext_vector_type(4)));

__global__ __launch_bounds__(256, 8) void tucker_fwd(
    const float* __restrict__ A, const float* __restrict__ B,
    const float* __restrict__ C, const float* __restrict__ G,
    float* __restrict__ out)
{
    const int tid = threadIdx.x;
    const int jlane = tid & 127;     // 128 lanes cover one row's 128 f32x4 chunks
    const int rslot = tid >> 7;      // 2 row-slots x 32 rows = 64 rows per block
    const int rowBase = blockIdx.x * 64;
    const int i = rowBase >> 9;      // uniform across the block (64 | 512)

    // This thread's 4 B rows (j = jlane*4 + e); each B row is one float4 (R2=4).
    const float4* B4 = reinterpret_cast<const float4*>(B);
    float4 b0 = B4[jlane * 4 + 0];
    float4 b1 = B4[jlane * 4 + 1];
    float4 b2 = B4[jlane * 4 + 2];
    float4 b3 = B4[jlane * 4 + 3];

    // W = row i of A@G (16 values), c = p*4 + q  (G is (4,16) row-major)
    const float4 a = reinterpret_cast<const float4*>(A)[i];
    float W[16];
#pragma unroll
    for (int c = 0; c < 16; ++c)
        W[c] = a.x * G[c] + a.y * G[16 + c] + a.z * G[32 + c] + a.w * G[48 + c];

    const float4* C4 = reinterpret_cast<const float4*>(C);
    const int row0 = rowBase + rslot * 32;
    f32x4* obase = reinterpret_cast<f32x4*>(out + (size_t)row0 * J_DIM) + jlane;

#pragma unroll 2
    for (int rr = 0; rr < 32; ++rr) {
        const float4 ck = C4[(row0 + rr) & 511];
        const float v0 = ck.x * W[0] + ck.y * W[4] + ck.z * W[8]  + ck.w * W[12];
        const float v1 = ck.x * W[1] + ck.y * W[5] + ck.z * W[9]  + ck.w * W[13];
        const float v2 = ck.x * W[2] + ck.y * W[6] + ck.z * W[10] + ck.w * W[14];
        const float v3 = ck.x * W[3] + ck.y * W[7] + ck.z * W[11] + ck.w * W[15];

        f32x4 o;
        o.x = v0 * b0.x + v1 * b0.y + v2 * b0.z + v3 * b0.w;
        o.y = v0 * b1.x + v1 * b1.y + v2 * b1.z + v3 * b1.w;
        o.z = v0 * b2.x + v1 * b2.y + v2 * b2.z + v3 * b2.w;
        o.w = v0 * b3.x + v1 * b3.y + v2 * b3.z + v3 * b3.w;
        __builtin_nontemporal_store(o, obase + (size_t)rr * 128);
    }
}

extern "C" void kernel_launch(void* const* d_in, const int* in_sizes, int n_in,
                              void* d_out, int out_size, void* d_ws, size_t ws_size,
                              hipStream_t stream) {
    const float* A = (const float*)d_in[0];   // (512, 4)
    const float* B = (const float*)d_in[1];   // (512, 4)
    const float* C = (const float*)d_in[2];   // (512, 4)
    const float* G = (const float*)d_in[3];   // (4, 16)
    float* out = (float*)d_out;               // (512, 512*512) f32

    tucker_fwd<<<4096, 256, 0, stream>>>(A, B, C, G, out);
}

// Round 7
// 96.909 us; speedup vs baseline: 1.2573x; 1.0667x over previous
//
#include <hip/hip_runtime.h>

// DirectTuckerNet forward: out[i, k*J + j] = sum_{p,q} M[i,p,q] * C[k,p] * B[j,q]
// with M = (A @ G).reshape(I, R3, R2).  I=J=K=512, R1=R2=R3=4.
//
//   W[c]  = sum_r A[i,r] * G[r,c]          (once per thread; i uniform per block)
//   v[q]  = sum_p C[k,p] * W[p*4+q]        (per row)
//   out[i,k,j] = sum_q v[q] * B[j,q]       (4 FMA per element)
//
// Geometry = R4 (best so far: 96us): 2048 blocks x 256 thr, 32 j-lanes x 8
// row-slots, 16 rows/thread, 16 j/thread in registers, NT stores.
// Change vs R4: per row, compute ALL FOUR o-vectors into registers BEFORE any
// store, so the 4 NT global_store_dwordx4 issue back-to-back -> 4x per-wave
// outstanding-store depth at the same occupancy (~119 VGPR, 4 waves/SIMD).

#define J_DIM 512

typedef float f32x4 __attribute__((ext_vector_type(4)));

__global__ __launch_bounds__(256) void tucker_fwd(
    const float* __restrict__ A, const float* __restrict__ B,
    const float* __restrict__ C, const float* __restrict__ G,
    float* __restrict__ out)
{
    const int tid = threadIdx.x;
    const int jlane = tid & 31;      // 32 j-lanes cover 512 j's (16 j each)
    const int rslot = tid >> 5;      // 8 row-slots x 16 rows = 128 rows per block
    const int rowBase = blockIdx.x * 128;
    const int i = rowBase >> 9;      // uniform across the block (128 | 512)

    // Load this thread's 16 B rows (j = s*128 + jlane*4 + e) into registers.
    const float4* B4 = reinterpret_cast<const float4*>(B);
    float4 b[4][4];
#pragma unroll
    for (int s = 0; s < 4; ++s) {
        const int j0 = s * 128 + jlane * 4;
#pragma unroll
        for (int e = 0; e < 4; ++e) b[s][e] = B4[j0 + e];
    }

    // W = row i of A@G (16 values), c = p*4 + q  (G is (4,16) row-major)
    const float4 a = reinterpret_cast<const float4*>(A)[i];
    float W[16];
#pragma unroll
    for (int c = 0; c < 16; ++c)
        W[c] = a.x * G[c] + a.y * G[16 + c] + a.z * G[32 + c] + a.w * G[48 + c];

    const float4* C4 = reinterpret_cast<const float4*>(C);
    const int row0 = rowBase + rslot * 16;
    f32x4* obase = reinterpret_cast<f32x4*>(out + (size_t)row0 * J_DIM) + jlane;

    for (int rr = 0; rr < 16; ++rr) {
        const float4 ck = C4[(row0 + rr) & 511];
        const float v0 = ck.x * W[0] + ck.y * W[4] + ck.z * W[8]  + ck.w * W[12];
        const float v1 = ck.x * W[1] + ck.y * W[5] + ck.z * W[9]  + ck.w * W[13];
        const float v2 = ck.x * W[2] + ck.y * W[6] + ck.z * W[10] + ck.w * W[14];
        const float v3 = ck.x * W[3] + ck.y * W[7] + ck.z * W[11] + ck.w * W[15];

        // Compute all four output vectors first...
        f32x4 o[4];
#pragma unroll
        for (int s = 0; s < 4; ++s) {
            o[s].x = v0 * b[s][0].x + v1 * b[s][0].y + v2 * b[s][0].z + v3 * b[s][0].w;
            o[s].y = v0 * b[s][1].x + v1 * b[s][1].y + v2 * b[s][1].z + v3 * b[s][1].w;
            o[s].z = v0 * b[s][2].x + v1 * b[s][2].y + v2 * b[s][2].z + v3 * b[s][2].w;
            o[s].w = v0 * b[s][3].x + v1 * b[s][3].y + v2 * b[s][3].z + v3 * b[s][3].w;
        }
        // ...then issue the 4 NT stores back-to-back (deep store clustering).
        f32x4* orow = obase + (size_t)rr * 128;
#pragma unroll
        for (int s = 0; s < 4; ++s)
            __builtin_nontemporal_store(o[s], orow + s * 32);
    }
}

extern "C" void kernel_launch(void* const* d_in, const int* in_sizes, int n_in,
                              void* d_out, int out_size, void* d_ws, size_t ws_size,
                              hipStream_t stream) {
    const float* A = (const float*)d_in[0];   // (512, 4)
    const float* B = (const float*)d_in[1];   // (512, 4)
    const float* C = (const float*)d_in[2];   // (512, 4)
    const float* G = (const float*)d_in[3];   // (4, 16)
    float* out = (float*)d_out;               // (512, 512*512) f32

    tucker_fwd<<<2048, 256, 0, stream>>>(A, B, C, G, out);
}